// Round 1
// baseline (97.221 us; speedup 1.0000x reference)
//
#include <hip/hip_runtime.h>

#define NB 2048
#define BS 256
#define NWAVES (BS / 64)

// Kernel A: grid-stride over points (2 points per float4 load).
// Accumulates sum of exp(-0.5*((d-2)/4)^2) (un-normalized) and inside-count,
// reduces within block, writes partials[b] = sum, partials[NB+b] = count.
__global__ __launch_bounds__(BS) void reduce_kernel(
    const float* __restrict__ pts, const float* __restrict__ cam,
    float* __restrict__ partials, int n_points) {
  const float cx = cam[0], cy = cam[1], yaw = cam[2];
  const float c = cosf(yaw), s = sinf(yaw);
  // verts = POLY @ rot.T + pose[:2], POLY = (0,0),(2,7),(-2,7)
  const float v0x = cx,                    v0y = cy;
  const float v1x = 2.f * c - 7.f * s + cx, v1y = 2.f * s + 7.f * c + cy;
  const float v2x = -2.f * c - 7.f * s + cx, v2y = -2.f * s + 7.f * c + cy;
  const float e0x = v1x - v0x, e0y = v1y - v0y;
  const float e1x = v2x - v1x, e1y = v2y - v1y;
  const float e2x = v0x - v2x, e2y = v0y - v2y;

  float sum_g = 0.f;
  float cnt = 0.f;

  const int tid = blockIdx.x * BS + threadIdx.x;
  const int stride = NB * BS;
  const int n4 = n_points >> 1;  // one float4 = 2 points
  const float4* __restrict__ p4 = (const float4*)pts;

  for (int i = tid; i < n4; i += stride) {
    float4 p = p4[i];
    {
      const float px = p.x, py = p.y;
      const float dx = cx - px, dy = cy - py;
      const float d = sqrtf(dx * dx + dy * dy);
      const float t = (d - 2.0f) * 0.25f;
      sum_g += expf(-0.5f * t * t);
      const float c0 = e0x * (py - v0y) - e0y * (px - v0x);
      const float c1 = e1x * (py - v1y) - e1y * (px - v1x);
      const float c2 = e2x * (py - v2y) - e2y * (px - v2x);
      const bool inside = (c0 > 0.f && c1 > 0.f && c2 > 0.f) ||
                          (c0 < 0.f && c1 < 0.f && c2 < 0.f);
      cnt += inside ? 1.f : 0.f;
    }
    {
      const float px = p.z, py = p.w;
      const float dx = cx - px, dy = cy - py;
      const float d = sqrtf(dx * dx + dy * dy);
      const float t = (d - 2.0f) * 0.25f;
      sum_g += expf(-0.5f * t * t);
      const float c0 = e0x * (py - v0y) - e0y * (px - v0x);
      const float c1 = e1x * (py - v1y) - e1y * (px - v1x);
      const float c2 = e2x * (py - v2y) - e2y * (px - v2x);
      const bool inside = (c0 > 0.f && c1 > 0.f && c2 > 0.f) ||
                          (c0 < 0.f && c1 < 0.f && c2 < 0.f);
      cnt += inside ? 1.f : 0.f;
    }
  }
  // odd-N tail (not hit for N=8M, kept for generality)
  if (tid == 0 && (n_points & 1)) {
    const float px = pts[2 * (n_points - 1)], py = pts[2 * (n_points - 1) + 1];
    const float dx = cx - px, dy = cy - py;
    const float d = sqrtf(dx * dx + dy * dy);
    const float t = (d - 2.0f) * 0.25f;
    sum_g += expf(-0.5f * t * t);
    const float c0 = e0x * (py - v0y) - e0y * (px - v0x);
    const float c1 = e1x * (py - v1y) - e1y * (px - v1x);
    const float c2 = e2x * (py - v2y) - e2y * (px - v2x);
    const bool inside = (c0 > 0.f && c1 > 0.f && c2 > 0.f) ||
                        (c0 < 0.f && c1 < 0.f && c2 < 0.f);
    cnt += inside ? 1.f : 0.f;
  }

  // wave (64-lane) shuffle reduction
  for (int off = 32; off > 0; off >>= 1) {
    sum_g += __shfl_down(sum_g, off, 64);
    cnt += __shfl_down(cnt, off, 64);
  }
  __shared__ float ls[NWAVES], lc[NWAVES];
  const int lane = threadIdx.x & 63, wid = threadIdx.x >> 6;
  if (lane == 0) { ls[wid] = sum_g; lc[wid] = cnt; }
  __syncthreads();
  if (threadIdx.x == 0) {
    float S = 0.f, C = 0.f;
    for (int w = 0; w < NWAVES; ++w) { S += ls[w]; C += lc[w]; }
    partials[blockIdx.x] = S;
    partials[NB + blockIdx.x] = C;
  }
}

// Kernel B: one block reduces NB partial pairs and writes the scalar output.
__global__ __launch_bounds__(BS) void finalize_kernel(
    const float* __restrict__ partials, float* __restrict__ out) {
  float S = 0.f, C = 0.f;
  for (int i = threadIdx.x; i < NB; i += BS) {
    S += partials[i];
    C += partials[NB + i];
  }
  for (int off = 32; off > 0; off >>= 1) {
    S += __shfl_down(S, off, 64);
    C += __shfl_down(C, off, 64);
  }
  __shared__ float ls[NWAVES], lc[NWAVES];
  const int lane = threadIdx.x & 63, wid = threadIdx.x >> 6;
  if (lane == 0) { ls[wid] = S; lc[wid] = C; }
  __syncthreads();
  if (threadIdx.x == 0) {
    float St = 0.f, Ct = 0.f;
    for (int w = 0; w < NWAVES; ++w) { St += ls[w]; Ct += lc[w]; }
    // gaussian norm: 1/(sigma*sqrt(2*pi)), sigma=4
    const float K = 0.09973557010f;
    const float eps = 1e-6f;
    out[0] = 1.0f / (St * K + eps) + 1.0f / (Ct + eps);
  }
}

extern "C" void kernel_launch(void* const* d_in, const int* in_sizes, int n_in,
                              void* d_out, int out_size, void* d_ws, size_t ws_size,
                              hipStream_t stream) {
  const float* pts = (const float*)d_in[0];
  const float* cam = (const float*)d_in[1];
  float* out = (float*)d_out;
  float* partials = (float*)d_ws;  // 2*NB floats = 16 KB
  const int n_points = in_sizes[0] / 2;

  reduce_kernel<<<NB, BS, 0, stream>>>(pts, cam, partials, n_points);
  finalize_kernel<<<1, BS, 0, stream>>>(partials, out);
}